// Round 6
// baseline (338.871 us; speedup 1.0000x reference)
//
#include <hip/hip_runtime.h>

typedef unsigned short u16;
typedef unsigned int u32;
typedef __attribute__((ext_vector_type(8))) short short8;
typedef __attribute__((ext_vector_type(4))) float f32x4;

#define BB 8
#define CCH 256
#define HH 64
#define WW 64
#define HP 66
#define NPOS 4096
#define KTOT 2304

// ---- ws layout (bytes) ----
#define XT_BYTES   17842176ull                 // bf16 [8][66][66][256]
#define W2R_OFF    17842176ull                 // bf16 [256][2304]
#define WOFF2_OFF  19021824ull                 // bf16 [32][2304]
#define P_OFF      19169280ull                 // fp32 [8][9][18][4096] partials
#define OFF2_OFF   40402944ull                 // float2 [8][9][4096]
#define S_OFF      42762240ull                 // bf16 [nb][9][4096][256]
#define S_BATCH    18874368ull                 // bytes per batch

__device__ __forceinline__ float bf2f(u16 u) {
    union { u32 u; float f; } v; v.u = ((u32)u) << 16; return v.f;
}
__device__ __forceinline__ u16 f2bf(float f) {
    union { float f; u32 u; } v; v.f = f;
    u32 r = v.u + 0x7FFFu + ((v.u >> 16) & 1u);
    return (u16)(r >> 16);
}
__device__ __forceinline__ u32 pk2(float a, float b) {
    return (u32)f2bf(a) | ((u32)f2bf(b) << 16);
}
__device__ __forceinline__ void bf2x2(u32 p, float& a, float& b) {
    union { u32 u; float f; } va, vb;
    va.u = p << 16; vb.u = p & 0xffff0000u;
    a = va.f; b = vb.f;
}
// async global->LDS, 16B per lane; LDS dest = wave-uniform base + lane*16
__device__ __forceinline__ void ldg_lds16(const u16* g, u16* l) {
    __builtin_amdgcn_global_load_lds((const __attribute__((address_space(1))) u32*)g,
                                     (__attribute__((address_space(3))) u32*)l, 16, 0, 0);
}

// ---- K0: reorder weights via LDS transpose: W2r[o][k*256+c] = w[o][c][k] ----
__global__ __launch_bounds__(256) void k_prep(const float* __restrict__ w, const float* __restrict__ w_off,
                                              u16* __restrict__ W2r, u16* __restrict__ Woff2) {
    __shared__ float L[2304];
    int t = threadIdx.x;
    if (blockIdx.x < 256) {
        int o = blockIdx.x;
        const float* src = w + (size_t)o * 2304;
#pragma unroll
        for (int j = 0; j < 9; ++j) L[j * 256 + t] = src[j * 256 + t];
        __syncthreads();
        u16* dst = W2r + (size_t)o * 2304;
#pragma unroll
        for (int k = 0; k < 9; ++k) dst[k * 256 + t] = f2bf(L[t * 9 + k]);   // stride-9: conflict-free
    } else {
        for (int o2 = 0; o2 < 32; ++o2) {
            if (o2 < 18) {
                const float* src = w_off + (size_t)o2 * 2304;
#pragma unroll
                for (int j = 0; j < 9; ++j) L[j * 256 + t] = src[j * 256 + t];
                __syncthreads();
#pragma unroll
                for (int k = 0; k < 9; ++k) Woff2[(size_t)o2 * 2304 + k * 256 + t] = f2bf(L[t * 9 + k]);
                __syncthreads();
            } else {
#pragma unroll
                for (int k = 0; k < 9; ++k) Woff2[(size_t)o2 * 2304 + k * 256 + t] = 0;
            }
        }
    }
}

// ---- K0b: zero the 1-px padding border of xT (replaces full memset) ----
__global__ void k_border(u16* __restrict__ xT) {
    int b = blockIdx.x, m = blockIdx.y;
    int y, x;
    if (m < 66)       { y = 0;  x = m; }
    else if (m < 132) { y = 65; x = m - 66; }
    else if (m < 196) { y = m - 132 + 1; x = 0; }
    else              { y = m - 196 + 1; x = 65; }
    u16* p = xT + ((size_t)(b * HP + y) * HP + x) * CCH + threadIdx.x * 4;
    uint2 zz; zz.x = 0; zz.y = 0;
    *(uint2*)p = zz;
}

// ---- K1: transpose+pad fp32 NCHW -> bf16 NHWC padded; x = batch (XCD-pinned) ----
__global__ __launch_bounds__(256) void k_transpose(const float* __restrict__ x, u16* __restrict__ xT) {
    __shared__ __align__(16) float T[64][72];
    int b = blockIdx.x, y = blockIdx.y, c0 = blockIdx.z * 64;
    int t = threadIdx.x;
    {
        int i = t >> 2, seg = t & 3;   // channel i, 16-float x-segment
        const float* src = x + (((size_t)(b * CCH + c0 + i) * HH + y) * WW) + seg * 16;
        float4 v0 = *(const float4*)(src);
        float4 v1 = *(const float4*)(src + 4);
        float4 v2 = *(const float4*)(src + 8);
        float4 v3 = *(const float4*)(src + 12);
        *(float4*)&T[i][seg * 16]      = v0;
        *(float4*)&T[i][seg * 16 + 4]  = v1;
        *(float4*)&T[i][seg * 16 + 8]  = v2;
        *(float4*)&T[i][seg * 16 + 12] = v3;
    }
    __syncthreads();
    {
        int xc = t >> 2, cs = t & 3;   // x-position xc, 16-channel segment cs
        u16* dst = xT + (((size_t)(b * HP + y + 1) * HP) + (xc + 1)) * CCH + c0 + cs * 16;
        u32 p[8];
#pragma unroll
        for (int j = 0; j < 8; ++j)
            p[j] = pk2(T[cs * 16 + 2 * j][xc], T[cs * 16 + 2 * j + 1][xc]);
        uint4 d0, d1;
        d0.x = p[0]; d0.y = p[1]; d0.z = p[2]; d0.w = p[3];
        d1.x = p[4]; d1.y = p[5]; d1.z = p[6]; d1.w = p[7];
        *(uint4*)dst = d0;
        *(uint4*)(dst + 8) = d1;
    }
}

// ---- K2: offset conv GEMM, K-split by tap; partial stores; x = batch ----
__global__ __launch_bounds__(256) void k_offconv(const u16* __restrict__ xT,
                                                 const u16* __restrict__ Woff2,
                                                 float* __restrict__ P) {
    __shared__ __align__(16) u16 AS[2][1024];   // [q4][32 row][8c] = 2KB
    __shared__ __align__(16) u16 BS[2][4096];   // [q4][128 row][8c] = 8KB
    int b = blockIdx.x, k9 = blockIdx.y;
    int pos0 = blockIdx.z * 128;
    int ky = k9 / 3, kx = k9 % 3;
    int t = threadIdx.x, lane = t & 63, wv = t >> 6;

    int rB = t & 127, qB = t >> 7;
    int posB = pos0 + rB;
    const u16* pB0 = xT + (((size_t)(b * HP + (posB >> 6) + ky) * HP) + (posB & 63) + kx) * CCH + qB * 8;
    const u16* pB1 = pB0 + 16;   // q+2
    const u16* pA0 = Woff2 + (size_t)(t & 31) * KTOT + k9 * 256 + (t >> 5) * 8;

    f32x4 acc[2][2];
    f32x4 z = {0.f, 0.f, 0.f, 0.f};
    acc[0][0] = z; acc[0][1] = z; acc[1][0] = z; acc[1][1] = z;

    if (t < 128) ldg_lds16(pA0, &AS[0][wv * 512]);
    ldg_lds16(pB0, &BS[0][wv * 512]);
    ldg_lds16(pB1, &BS[0][2048 + wv * 512]);
    __syncthreads();

    int buf = 0;
    for (int cs = 0; cs < 8; ++cs) {
        if (cs < 7) {
            int d = (cs + 1) * 32;
            if (t < 128) ldg_lds16(pA0 + d, &AS[buf ^ 1][wv * 512]);
            ldg_lds16(pB0 + d, &BS[buf ^ 1][wv * 512]);
            ldg_lds16(pB1 + d, &BS[buf ^ 1][2048 + wv * 512]);
        }
        int q = lane >> 4, m = lane & 15;
        short8 a0 = *(const short8*)&AS[buf][(q * 32 + m) * 8];
        short8 a1 = *(const short8*)&AS[buf][(q * 32 + 16 + m) * 8];
        short8 b0 = *(const short8*)&BS[buf][(q * 128 + wv * 32 + m) * 8];
        short8 b1 = *(const short8*)&BS[buf][(q * 128 + wv * 32 + 16 + m) * 8];
        acc[0][0] = __builtin_amdgcn_mfma_f32_16x16x32_bf16(a0, b0, acc[0][0], 0, 0, 0);
        acc[0][1] = __builtin_amdgcn_mfma_f32_16x16x32_bf16(a0, b1, acc[0][1], 0, 0, 0);
        acc[1][0] = __builtin_amdgcn_mfma_f32_16x16x32_bf16(a1, b0, acc[1][0], 0, 0, 0);
        acc[1][1] = __builtin_amdgcn_mfma_f32_16x16x32_bf16(a1, b1, acc[1][1], 0, 0, 0);
        __syncthreads();
        buf ^= 1;
    }
    int q = lane >> 4, nn = lane & 15;
    float* Pp = P + (size_t)(b * 9 + k9) * 18 * NPOS;
#pragma unroll
    for (int ao = 0; ao < 2; ++ao)
#pragma unroll
        for (int bn = 0; bn < 2; ++bn) {
            int pos = pos0 + wv * 32 + bn * 16 + nn;
#pragma unroll
            for (int r = 0; r < 4; ++r) {
                int o = ao * 16 + q * 4 + r;
                if (o < 18) Pp[o * NPOS + pos] = acc[ao][bn][r];
            }
        }
}

// ---- K2b: reduce 9 tap-partials + bias -> off2[b][tap][pos] = (dy,dx) ----
__global__ __launch_bounds__(256) void k_reduce(const float* __restrict__ P,
                                                const float* __restrict__ b_off,
                                                float2* __restrict__ off2) {
    int b = blockIdx.x;
    int pos = blockIdx.y * 256 + threadIdx.x;
    float s[18];
#pragma unroll
    for (int o = 0; o < 18; ++o) s[o] = b_off[o];
    const float* Pp = P + (size_t)(b * 9) * 18 * NPOS + pos;
    for (int k9 = 0; k9 < 9; ++k9) {
#pragma unroll
        for (int o = 0; o < 18; ++o)
            s[o] += Pp[(k9 * 18 + o) * NPOS];
    }
#pragma unroll
    for (int op = 0; op < 9; ++op) {
        float2 v; v.x = s[2 * op]; v.y = s[2 * op + 1];
        off2[(((size_t)(b * 9 + op)) << 12) + pos] = v;
    }
}

// ---- K3: materialize S[bl][k9][pos][c] bf16; ONE WAVE PER POSITION (fully coalesced) ----
__global__ __launch_bounds__(256) void k_sample(const u16* __restrict__ xT,
                                                const float2* __restrict__ off2,
                                                u16* __restrict__ S, int b0) {
    int bl = blockIdx.x, b = b0 + bl, k9 = blockIdx.y;
    int t = threadIdx.x, lane = t & 63, wv = t >> 6;
    int pos0 = blockIdx.z * 256 + wv * 64;
    int ky = k9 / 3, kx = k9 % 3;
    int bbase = b * HP * HP;
    int c0 = lane * 4;   // 4 bf16 = 8B per lane -> 64 lanes cover 256ch = 512B contiguous

    for (int it = 0; it < 64; ++it) {
        int pos = pos0 + it;
        int y = pos >> 6, x = pos & 63;
        float2 off = off2[(((size_t)(b * 9 + k9)) << 12) + pos];   // wave-uniform
        float pyf = (float)(y - 1 + ky) + off.x;
        float pxf = (float)(x - 1 + kx) + off.y;
        float y0f = floorf(pyf), x0f = floorf(pxf);
        int y0 = (int)y0f, x0 = (int)x0f;
        int y1 = y0 + 1, x1 = x0 + 1;
        float wy1 = pyf - y0f, wy0 = 1.f - wy1;
        float wx1 = pxf - x0f, wx0 = 1.f - wx1;
        bool vy0 = (y0 >= 0) & (y0 < HH), vy1 = (y1 >= 0) & (y1 < HH);
        bool vx0 = (x0 >= 0) & (x0 < WW), vx1 = (x1 >= 0) & (x1 < WW);
        int yc0 = min(max(y0, 0), HH - 1), yc1 = min(max(y1, 0), HH - 1);
        int xc0 = min(max(x0, 0), WW - 1), xc1 = min(max(x1, 0), WW - 1);
        float w0 = (vy0 & vx0) ? wy0 * wx0 : 0.f;
        float w1 = (vy0 & vx1) ? wy0 * wx1 : 0.f;
        float w2 = (vy1 & vx0) ? wy1 * wx0 : 0.f;
        float w3 = (vy1 & vx1) ? wy1 * wx1 : 0.f;
        const u16* g0 = xT + (size_t)(bbase + (yc0 + 1) * HP + xc0 + 1) * CCH + c0;
        const u16* g1 = xT + (size_t)(bbase + (yc0 + 1) * HP + xc1 + 1) * CCH + c0;
        const u16* g2 = xT + (size_t)(bbase + (yc1 + 1) * HP + xc0 + 1) * CCH + c0;
        const u16* g3 = xT + (size_t)(bbase + (yc1 + 1) * HP + xc1 + 1) * CCH + c0;
        uint2 r0 = *(const uint2*)g0;
        uint2 r1 = *(const uint2*)g1;
        uint2 r2 = *(const uint2*)g2;
        uint2 r3 = *(const uint2*)g3;
        float f0a, f0b, f0c, f0d, f1a, f1b, f1c, f1d;
        float f2a, f2b, f2c, f2d, f3a, f3b, f3c, f3d;
        bf2x2(r0.x, f0a, f0b); bf2x2(r0.y, f0c, f0d);
        bf2x2(r1.x, f1a, f1b); bf2x2(r1.y, f1c, f1d);
        bf2x2(r2.x, f2a, f2b); bf2x2(r2.y, f2c, f2d);
        bf2x2(r3.x, f3a, f3b); bf2x2(r3.y, f3c, f3d);
        float v0 = w0 * f0a + w1 * f1a + w2 * f2a + w3 * f3a;
        float v1 = w0 * f0b + w1 * f1b + w2 * f2b + w3 * f3b;
        float v2 = w0 * f0c + w1 * f1c + w2 * f2c + w3 * f3c;
        float v3 = w0 * f0d + w1 * f1d + w2 * f2d + w3 * f3d;
        uint2 sv;
        sv.x = pk2(v0, v1); sv.y = pk2(v2, v3);
        *(uint2*)(S + ((((size_t)(bl * 9 + k9)) << 12) + pos) * CCH + c0) = sv;
    }
}

// ---- K4: GEMM tile 64(o) x 128(pos), BK=32, dbuf 24KB, grid nb*4*32 = 4 blocks/CU ----
__global__ __launch_bounds__(256) void k_gemm(const u16* __restrict__ S,
                                              const u16* __restrict__ W2r,
                                              const float* __restrict__ bias,
                                              float* __restrict__ out, int b0) {
    __shared__ __align__(16) u16 AS[2][2048];   // [q4][64 row][8c] = 4KB
    __shared__ __align__(16) u16 BS[2][4096];   // [q4][128 row][8c] = 8KB
    int bl = blockIdx.x, b = b0 + bl;
    int o0 = blockIdx.y * 64;
    int pos0 = blockIdx.z * 128;
    int t = threadIdx.x, lane = t & 63, wv = t >> 6;
    int wr = wv >> 1, wc = wv & 1;

    // A staging: slot t -> row = lane, q = wv
    const u16* pA = W2r + (size_t)(o0 + lane) * KTOT + wv * 8;
    // B staging: slots t, t+256 -> row = s&127, q = s>>7
    const u16* pB0 = S + ((((size_t)(bl * 9)) << 12) + pos0 + (t & 127)) * CCH + (t >> 7) * 8;
    const u16* pB1 = pB0 + 16;   // q+2

    f32x4 acc[2][4];
    f32x4 z = {0.f, 0.f, 0.f, 0.f};
#pragma unroll
    for (int i = 0; i < 2; ++i)
#pragma unroll
        for (int j = 0; j < 4; ++j) acc[i][j] = z;

    // prologue: step 0 into buf 0
    ldg_lds16(pA, &AS[0][wv * 512]);
    ldg_lds16(pB0, &BS[0][wv * 512]);
    ldg_lds16(pB1, &BS[0][2048 + wv * 512]);
    __syncthreads();

    int buf = 0;
    for (int step = 0; step < 72; ++step) {
        if (step < 71) {
            int ns = step + 1;
            int offA = (ns >> 3) * 256 + (ns & 7) * 32;
            size_t offB = (size_t)(ns >> 3) * (NPOS * CCH) + (ns & 7) * 32;
            ldg_lds16(pA + offA, &AS[buf ^ 1][wv * 512]);
            ldg_lds16(pB0 + offB, &BS[buf ^ 1][wv * 512]);
            ldg_lds16(pB1 + offB, &BS[buf ^ 1][2048 + wv * 512]);
        }
        int q = lane >> 4, m = lane & 15;
        short8 af[2], bfr[4];
#pragma unroll
        for (int ao = 0; ao < 2; ++ao)
            af[ao] = *(const short8*)&AS[buf][(q * 64 + wr * 32 + ao * 16 + m) * 8];
#pragma unroll
        for (int bn = 0; bn < 4; ++bn)
            bfr[bn] = *(const short8*)&BS[buf][(q * 128 + wc * 64 + bn * 16 + m) * 8];
#pragma unroll
        for (int ao = 0; ao < 2; ++ao)
#pragma unroll
            for (int bn = 0; bn < 4; ++bn)
                acc[ao][bn] = __builtin_amdgcn_mfma_f32_16x16x32_bf16(af[ao], bfr[bn], acc[ao][bn], 0, 0, 0);
        __syncthreads();
        buf ^= 1;
    }

    // epilogue: bias + sigmoid -> fp32 NCHW
    int q = lane >> 4, nn = lane & 15;
#pragma unroll
    for (int ao = 0; ao < 2; ++ao) {
        int ob = o0 + wr * 32 + ao * 16 + q * 4;
#pragma unroll
        for (int bn = 0; bn < 4; ++bn) {
            int pos = pos0 + wc * 64 + bn * 16 + nn;
#pragma unroll
            for (int r = 0; r < 4; ++r) {
                float v = acc[ao][bn][r] + bias[ob + r];
                float sg = 1.0f / (1.0f + __expf(-v));
                out[(size_t)((b * CCH + ob + r) * NPOS) + pos] = sg;
            }
        }
    }
}

extern "C" void kernel_launch(void* const* d_in, const int* in_sizes, int n_in,
                              void* d_out, int out_size, void* d_ws, size_t ws_size,
                              hipStream_t stream) {
    const float* x     = (const float*)d_in[0];
    const float* w_off = (const float*)d_in[1];
    const float* b_off = (const float*)d_in[2];
    const float* w     = (const float*)d_in[3];
    const float* bias  = (const float*)d_in[4];
    float* out = (float*)d_out;

    char* ws = (char*)d_ws;
    u16*    xT    = (u16*)ws;
    u16*    W2r   = (u16*)(ws + W2R_OFF);
    u16*    Woff2 = (u16*)(ws + WOFF2_OFF);
    float*  P     = (float*)(ws + P_OFF);
    float2* off2  = (float2*)(ws + OFF2_OFF);
    u16*    S     = (u16*)(ws + S_OFF);

    // batches per S-pass, adaptive to ws size
    int nb = 8;
    while (nb > 1 && ws_size < S_OFF + (size_t)nb * S_BATCH) nb >>= 1;
    if (ws_size < S_OFF + S_BATCH) return;

    k_prep<<<257, 256, 0, stream>>>(w, w_off, W2r, Woff2);
    k_border<<<dim3(8, 260), 64, 0, stream>>>(xT);
    k_transpose<<<dim3(8, 64, 4), 256, 0, stream>>>(x, xT);
    k_offconv<<<dim3(8, 9, 32), 256, 0, stream>>>(xT, Woff2, P);
    k_reduce<<<dim3(8, 16), 256, 0, stream>>>(P, b_off, off2);
    for (int p = 0; p < 8; p += nb) {
        k_sample<<<dim3(nb, 9, 16), 256, 0, stream>>>(xT, off2, S, p);
        k_gemm<<<dim3(nb, 4, 32), 256, 0, stream>>>(S, W2r, bias, out, p);
    }
}

// Round 7
// 250.621 us; speedup vs baseline: 1.3521x; 1.3521x over previous
//
#include <hip/hip_runtime.h>

typedef unsigned short u16;
typedef unsigned int u32;
typedef __attribute__((ext_vector_type(8))) short short8;
typedef __attribute__((ext_vector_type(4))) float f32x4;

#define BB 8
#define CCH 256
#define HH 64
#define WW 64
#define HP 66
#define NPOS 4096
#define KTOT 2304

// ---- ws layout (bytes) ----
#define XT_BYTES   17842176ull                 // bf16 [8][66][66][256]
#define W2R_OFF    17842176ull                 // bf16 [256][2304]
#define WOFF2_OFF  19021824ull                 // bf16 [32][2304]
#define P_OFF      19169280ull                 // fp32 [8][9][18][4096] partials
#define OFF2_OFF   40402944ull                 // float2 [8][9][4096]
#define S_OFF      42762240ull                 // bf16 [nb][9][4096][256]
#define S_BATCH    18874368ull                 // bytes per batch

__device__ __forceinline__ float bf2f(u16 u) {
    union { u32 u; float f; } v; v.u = ((u32)u) << 16; return v.f;
}
__device__ __forceinline__ u16 f2bf(float f) {
    union { float f; u32 u; } v; v.f = f;
    u32 r = v.u + 0x7FFFu + ((v.u >> 16) & 1u);
    return (u16)(r >> 16);
}
__device__ __forceinline__ u32 pk2(float a, float b) {
    return (u32)f2bf(a) | ((u32)f2bf(b) << 16);
}
__device__ __forceinline__ void bf2x2(u32 p, float& a, float& b) {
    union { u32 u; float f; } va, vb;
    va.u = p << 16; vb.u = p & 0xffff0000u;
    a = va.f; b = vb.f;
}
// async global->LDS, 16B per lane; LDS dest = wave-uniform base + lane*16
__device__ __forceinline__ void ldg_lds16(const u16* g, u16* l) {
    __builtin_amdgcn_global_load_lds((const __attribute__((address_space(1))) u32*)g,
                                     (__attribute__((address_space(3))) u32*)l, 16, 0, 0);
}

// ---- K0: reorder weights via LDS transpose: W2r[o][k*256+c] = w[o][c][k] ----
__global__ __launch_bounds__(256) void k_prep(const float* __restrict__ w, const float* __restrict__ w_off,
                                              u16* __restrict__ W2r, u16* __restrict__ Woff2) {
    __shared__ float L[2304];
    int t = threadIdx.x;
    if (blockIdx.x < 256) {
        int o = blockIdx.x;
        const float* src = w + (size_t)o * 2304;
#pragma unroll
        for (int j = 0; j < 9; ++j) L[j * 256 + t] = src[j * 256 + t];
        __syncthreads();
        u16* dst = W2r + (size_t)o * 2304;
#pragma unroll
        for (int k = 0; k < 9; ++k) dst[k * 256 + t] = f2bf(L[t * 9 + k]);   // stride-9: conflict-free
    } else {
        for (int o2 = 0; o2 < 32; ++o2) {
            if (o2 < 18) {
                const float* src = w_off + (size_t)o2 * 2304;
#pragma unroll
                for (int j = 0; j < 9; ++j) L[j * 256 + t] = src[j * 256 + t];
                __syncthreads();
#pragma unroll
                for (int k = 0; k < 9; ++k) Woff2[(size_t)o2 * 2304 + k * 256 + t] = f2bf(L[t * 9 + k]);
                __syncthreads();
            } else {
#pragma unroll
                for (int k = 0; k < 9; ++k) Woff2[(size_t)o2 * 2304 + k * 256 + t] = 0;
            }
        }
    }
}

// ---- K0b: zero the 1-px padding border of xT (replaces full memset) ----
__global__ void k_border(u16* __restrict__ xT) {
    int b = blockIdx.x, m = blockIdx.y;
    int y, x;
    if (m < 66)       { y = 0;  x = m; }
    else if (m < 132) { y = 65; x = m - 66; }
    else if (m < 196) { y = m - 132 + 1; x = 0; }
    else              { y = m - 196 + 1; x = 65; }
    u16* p = xT + ((size_t)(b * HP + y) * HP + x) * CCH + threadIdx.x * 4;
    uint2 zz; zz.x = 0; zz.y = 0;
    *(uint2*)p = zz;
}

// ---- K1: transpose+pad fp32 NCHW -> bf16 NHWC padded; x = batch (XCD-pinned) ----
__global__ __launch_bounds__(256) void k_transpose(const float* __restrict__ x, u16* __restrict__ xT) {
    __shared__ __align__(16) float T[64][72];
    int b = blockIdx.x, y = blockIdx.y, c0 = blockIdx.z * 64;
    int t = threadIdx.x;
    {
        int i = t >> 2, seg = t & 3;   // channel i, 16-float x-segment
        const float* src = x + (((size_t)(b * CCH + c0 + i) * HH + y) * WW) + seg * 16;
        float4 v0 = *(const float4*)(src);
        float4 v1 = *(const float4*)(src + 4);
        float4 v2 = *(const float4*)(src + 8);
        float4 v3 = *(const float4*)(src + 12);
        *(float4*)&T[i][seg * 16]      = v0;
        *(float4*)&T[i][seg * 16 + 4]  = v1;
        *(float4*)&T[i][seg * 16 + 8]  = v2;
        *(float4*)&T[i][seg * 16 + 12] = v3;
    }
    __syncthreads();
    {
        int xc = t >> 2, cs = t & 3;   // x-position xc, 16-channel segment cs
        u16* dst = xT + (((size_t)(b * HP + y + 1) * HP) + (xc + 1)) * CCH + c0 + cs * 16;
        u32 p[8];
#pragma unroll
        for (int j = 0; j < 8; ++j)
            p[j] = pk2(T[cs * 16 + 2 * j][xc], T[cs * 16 + 2 * j + 1][xc]);
        uint4 d0, d1;
        d0.x = p[0]; d0.y = p[1]; d0.z = p[2]; d0.w = p[3];
        d1.x = p[4]; d1.y = p[5]; d1.z = p[6]; d1.w = p[7];
        *(uint4*)dst = d0;
        *(uint4*)(dst + 8) = d1;
    }
}

// ---- K2: offset conv GEMM, K-split by tap; partial stores; x = batch ----
__global__ __launch_bounds__(256) void k_offconv(const u16* __restrict__ xT,
                                                 const u16* __restrict__ Woff2,
                                                 float* __restrict__ P) {
    __shared__ __align__(16) u16 AS[2][1024];   // [q4][32 row][8c] = 2KB
    __shared__ __align__(16) u16 BS[2][4096];   // [q4][128 row][8c] = 8KB
    int b = blockIdx.x, k9 = blockIdx.y;
    int pos0 = blockIdx.z * 128;
    int ky = k9 / 3, kx = k9 % 3;
    int t = threadIdx.x, lane = t & 63, wv = t >> 6;

    int rB = t & 127, qB = t >> 7;
    int posB = pos0 + rB;
    const u16* pB0 = xT + (((size_t)(b * HP + (posB >> 6) + ky) * HP) + (posB & 63) + kx) * CCH + qB * 8;
    const u16* pB1 = pB0 + 16;   // q+2
    const u16* pA0 = Woff2 + (size_t)(t & 31) * KTOT + k9 * 256 + (t >> 5) * 8;

    f32x4 acc[2][2];
    f32x4 z = {0.f, 0.f, 0.f, 0.f};
    acc[0][0] = z; acc[0][1] = z; acc[1][0] = z; acc[1][1] = z;

    if (t < 128) ldg_lds16(pA0, &AS[0][wv * 512]);
    ldg_lds16(pB0, &BS[0][wv * 512]);
    ldg_lds16(pB1, &BS[0][2048 + wv * 512]);
    __syncthreads();

    int buf = 0;
    for (int cs = 0; cs < 8; ++cs) {
        if (cs < 7) {
            int d = (cs + 1) * 32;
            if (t < 128) ldg_lds16(pA0 + d, &AS[buf ^ 1][wv * 512]);
            ldg_lds16(pB0 + d, &BS[buf ^ 1][wv * 512]);
            ldg_lds16(pB1 + d, &BS[buf ^ 1][2048 + wv * 512]);
        }
        int q = lane >> 4, m = lane & 15;
        short8 a0 = *(const short8*)&AS[buf][(q * 32 + m) * 8];
        short8 a1 = *(const short8*)&AS[buf][(q * 32 + 16 + m) * 8];
        short8 b0 = *(const short8*)&BS[buf][(q * 128 + wv * 32 + m) * 8];
        short8 b1 = *(const short8*)&BS[buf][(q * 128 + wv * 32 + 16 + m) * 8];
        acc[0][0] = __builtin_amdgcn_mfma_f32_16x16x32_bf16(a0, b0, acc[0][0], 0, 0, 0);
        acc[0][1] = __builtin_amdgcn_mfma_f32_16x16x32_bf16(a0, b1, acc[0][1], 0, 0, 0);
        acc[1][0] = __builtin_amdgcn_mfma_f32_16x16x32_bf16(a1, b0, acc[1][0], 0, 0, 0);
        acc[1][1] = __builtin_amdgcn_mfma_f32_16x16x32_bf16(a1, b1, acc[1][1], 0, 0, 0);
        __syncthreads();
        buf ^= 1;
    }
    int q = lane >> 4, nn = lane & 15;
    float* Pp = P + (size_t)(b * 9 + k9) * 18 * NPOS;
#pragma unroll
    for (int ao = 0; ao < 2; ++ao)
#pragma unroll
        for (int bn = 0; bn < 2; ++bn) {
            int pos = pos0 + wv * 32 + bn * 16 + nn;
#pragma unroll
            for (int r = 0; r < 4; ++r) {
                int o = ao * 16 + q * 4 + r;
                if (o < 18) Pp[o * NPOS + pos] = acc[ao][bn][r];
            }
        }
}

// ---- K2b: reduce 9 tap-partials + bias -> off2[b][tap][pos] = (dy,dx) ----
__global__ __launch_bounds__(256) void k_reduce(const float* __restrict__ P,
                                                const float* __restrict__ b_off,
                                                float2* __restrict__ off2) {
    int b = blockIdx.x;
    int pos = blockIdx.y * 256 + threadIdx.x;
    float s[18];
#pragma unroll
    for (int o = 0; o < 18; ++o) s[o] = b_off[o];
    const float* Pp = P + (size_t)(b * 9) * 18 * NPOS + pos;
    for (int k9 = 0; k9 < 9; ++k9) {
#pragma unroll
        for (int o = 0; o < 18; ++o)
            s[o] += Pp[(k9 * 18 + o) * NPOS];
    }
#pragma unroll
    for (int op = 0; op < 9; ++op) {
        float2 v; v.x = s[2 * op]; v.y = s[2 * op + 1];
        off2[(((size_t)(b * 9 + op)) << 12) + pos] = v;
    }
}

// ---- K3: materialize S[bl][k9][pos][c] bf16 via 16-lane-group coalesced bilinear gather ----
__global__ __launch_bounds__(256) void k_sample(const u16* __restrict__ xT,
                                                const float2* __restrict__ off2,
                                                u16* __restrict__ S, int b0) {
    int bl = blockIdx.x, b = b0 + bl, k9 = blockIdx.y;
    int pos0 = blockIdx.z * 64;
    int t = threadIdx.x, g = t >> 4, ll = t & 15;
    int ky = k9 / 3, kx = k9 % 3;
    int bbase = b * HP * HP;

    for (int i = 0; i < 4; ++i) {
        int pos = pos0 + g + i * 16;
        int y = pos >> 6, x = pos & 63;
        float2 off = off2[(((size_t)(b * 9 + k9)) << 12) + pos];
        float pyf = (float)(y - 1 + ky) + off.x;
        float pxf = (float)(x - 1 + kx) + off.y;
        float y0f = floorf(pyf), x0f = floorf(pxf);
        int y0 = (int)y0f, x0 = (int)x0f;
        int y1 = y0 + 1, x1 = x0 + 1;
        float wy1 = pyf - y0f, wy0 = 1.f - wy1;
        float wx1 = pxf - x0f, wx0 = 1.f - wx1;
        bool vy0 = (y0 >= 0) & (y0 < HH), vy1 = (y1 >= 0) & (y1 < HH);
        bool vx0 = (x0 >= 0) & (x0 < WW), vx1 = (x1 >= 0) & (x1 < WW);
        int yc0 = min(max(y0, 0), HH - 1), yc1 = min(max(y1, 0), HH - 1);
        int xc0 = min(max(x0, 0), WW - 1), xc1 = min(max(x1, 0), WW - 1);
        float w0 = (vy0 & vx0) ? wy0 * wx0 : 0.f;
        float w1 = (vy0 & vx1) ? wy0 * wx1 : 0.f;
        float w2 = (vy1 & vx0) ? wy1 * wx0 : 0.f;
        float w3 = (vy1 & vx1) ? wy1 * wx1 : 0.f;
        const u16* g0 = xT + (size_t)((bbase + (yc0 + 1) * HP + xc0 + 1)) * CCH;
        const u16* g1 = xT + (size_t)((bbase + (yc0 + 1) * HP + xc1 + 1)) * CCH;
        const u16* g2 = xT + (size_t)((bbase + (yc1 + 1) * HP + xc0 + 1)) * CCH;
        const u16* g3 = xT + (size_t)((bbase + (yc1 + 1) * HP + xc1 + 1)) * CCH;
        u16* sp = S + ((((size_t)(bl * 9 + k9)) << 12) + pos) * CCH;
#pragma unroll
        for (int cp = 0; cp < 4; ++cp) {
            int c = cp * 64 + ll * 4;
            uint2 r0 = *(const uint2*)(g0 + c);
            uint2 r1 = *(const uint2*)(g1 + c);
            uint2 r2 = *(const uint2*)(g2 + c);
            uint2 r3 = *(const uint2*)(g3 + c);
            float f0a, f0b, f0c, f0d, f1a, f1b, f1c, f1d;
            float f2a, f2b, f2c, f2d, f3a, f3b, f3c, f3d;
            bf2x2(r0.x, f0a, f0b); bf2x2(r0.y, f0c, f0d);
            bf2x2(r1.x, f1a, f1b); bf2x2(r1.y, f1c, f1d);
            bf2x2(r2.x, f2a, f2b); bf2x2(r2.y, f2c, f2d);
            bf2x2(r3.x, f3a, f3b); bf2x2(r3.y, f3c, f3d);
            float v0 = w0 * f0a + w1 * f1a + w2 * f2a + w3 * f3a;
            float v1 = w0 * f0b + w1 * f1b + w2 * f2b + w3 * f3b;
            float v2 = w0 * f0c + w1 * f1c + w2 * f2c + w3 * f3c;
            float v3 = w0 * f0d + w1 * f1d + w2 * f2d + w3 * f3d;
            uint2 sv;
            sv.x = pk2(v0, v1); sv.y = pk2(v2, v3);
            *(uint2*)(sp + c) = sv;
        }
    }
}

// ---- K4: GEMM 128x128, BK=64, dbuf; row-major LDS + XOR-swizzled chunks so staging is
//      coalesced (8-lane groups read 128B contiguous: 16 lines/instr vs 64 before) ----
__global__ __launch_bounds__(256) void k_gemm(const u16* __restrict__ S,
                                              const u16* __restrict__ W2r,
                                              const float* __restrict__ bias,
                                              float* __restrict__ out, int b0) {
    __shared__ __align__(16) u16 AS[2][8192];   // [128 row][64 k] row-major, swizzled chunks, 16KB
    __shared__ __align__(16) u16 BS[2][8192];
    int bl = blockIdx.x, b = b0 + bl;
    int o0 = blockIdx.y * 128;
    int pos0 = blockIdx.z * 128;
    int t = threadIdx.x, lane = t & 63, wv = t >> 6;
    int wr = wv >> 1, wc = wv & 1;

    // staging lane geometry: instr inst covers rows inst*8..+8; lane: row=+lane>>3, slot=lane&7
    int srow = lane >> 3;                       // 0..7 row-within-instr (also swizzle key)
    int sw8 = ((lane & 7) ^ srow) << 3;         // swizzled global chunk offset (u16 elems)
    const u16* pA = W2r + (size_t)o0 * KTOT;    // + row*KTOT + koff + sw8
    const u16* pSb = S + (((size_t)(bl * 9)) << 12) * CCH;

    f32x4 acc[4][4];
    f32x4 z = {0.f, 0.f, 0.f, 0.f};
#pragma unroll
    for (int i = 0; i < 4; ++i)
#pragma unroll
        for (int j = 0; j < 4; ++j) acc[i][j] = z;

    // ---- stage step s into buf d ----
    auto stage = [&](int s, int d) {
        int k9 = s >> 2, cs = s & 3;
        int koffA = k9 * 256 + cs * 64;
        const u16* pB = pSb + ((size_t)k9 << 12) * CCH + cs * 64;
#pragma unroll
        for (int i = 0; i < 4; ++i) {
            int inst = wv * 4 + i;
            int row = inst * 8 + srow;
            ldg_lds16(pA + (size_t)row * KTOT + koffA + sw8, &AS[d][inst * 512]);
            ldg_lds16(pB + (size_t)(pos0 + row) * CCH + sw8, &BS[d][inst * 512]);
        }
    };

    stage(0, 0);
    __syncthreads();

    int buf = 0;
    int m = lane & 15, q = lane >> 4, key = lane & 7;
    for (int step = 0; step < 36; ++step) {
        if (step < 35) stage(step + 1, buf ^ 1);
#pragma unroll
        for (int j = 0; j < 2; ++j) {
            int slot8 = (((j * 4 + q) ^ key) << 3);
            short8 af[4], bfr[4];
#pragma unroll
            for (int ao = 0; ao < 4; ++ao)
                af[ao] = *(const short8*)&AS[buf][(wr * 64 + ao * 16 + m) * 64 + slot8];
#pragma unroll
            for (int bn = 0; bn < 4; ++bn)
                bfr[bn] = *(const short8*)&BS[buf][(wc * 64 + bn * 16 + m) * 64 + slot8];
#pragma unroll
            for (int ao = 0; ao < 4; ++ao)
#pragma unroll
                for (int bn = 0; bn < 4; ++bn)
                    acc[ao][bn] = __builtin_amdgcn_mfma_f32_16x16x32_bf16(af[ao], bfr[bn], acc[ao][bn], 0, 0, 0);
        }
        __syncthreads();
        buf ^= 1;
    }

    // epilogue: bias + sigmoid -> fp32 NCHW
    int nn = lane & 15;
#pragma unroll
    for (int ao = 0; ao < 4; ++ao) {
        int ob = o0 + wr * 64 + ao * 16 + q * 4;
#pragma unroll
        for (int bn = 0; bn < 4; ++bn) {
            int pos = pos0 + wc * 64 + bn * 16 + nn;
#pragma unroll
            for (int r = 0; r < 4; ++r) {
                float v = acc[ao][bn][r] + bias[ob + r];
                float sg = 1.0f / (1.0f + __expf(-v));
                out[(size_t)((b * CCH + ob + r) * NPOS) + pos] = sg;
            }
        }
    }
}

extern "C" void kernel_launch(void* const* d_in, const int* in_sizes, int n_in,
                              void* d_out, int out_size, void* d_ws, size_t ws_size,
                              hipStream_t stream) {
    const float* x     = (const float*)d_in[0];
    const float* w_off = (const float*)d_in[1];
    const float* b_off = (const float*)d_in[2];
    const float* w     = (const float*)d_in[3];
    const float* bias  = (const float*)d_in[4];
    float* out = (float*)d_out;

    char* ws = (char*)d_ws;
    u16*    xT    = (u16*)ws;
    u16*    W2r   = (u16*)(ws + W2R_OFF);
    u16*    Woff2 = (u16*)(ws + WOFF2_OFF);
    float*  P     = (float*)(ws + P_OFF);
    float2* off2  = (float2*)(ws + OFF2_OFF);
    u16*    S     = (u16*)(ws + S_OFF);

    // batches per S-pass, adaptive to ws size
    int nb = 8;
    while (nb > 1 && ws_size < S_OFF + (size_t)nb * S_BATCH) nb >>= 1;
    if (ws_size < S_OFF + S_BATCH) return;

    k_prep<<<257, 256, 0, stream>>>(w, w_off, W2r, Woff2);
    k_border<<<dim3(8, 260), 64, 0, stream>>>(xT);
    k_transpose<<<dim3(8, 64, 4), 256, 0, stream>>>(x, xT);
    k_offconv<<<dim3(8, 9, 32), 256, 0, stream>>>(xT, Woff2, P);
    k_reduce<<<dim3(8, 16), 256, 0, stream>>>(P, b_off, off2);
    for (int p = 0; p < 8; p += nb) {
        k_sample<<<dim3(nb, 9, 64), 256, 0, stream>>>(xT, off2, S, p);
        k_gemm<<<dim3(nb, 2, 32), 256, 0, stream>>>(S, W2r, bias, out, p);
    }
}

// Round 10
// 233.486 us; speedup vs baseline: 1.4514x; 1.0734x over previous
//
#include <hip/hip_runtime.h>

typedef unsigned short u16;
typedef unsigned int u32;
typedef __attribute__((ext_vector_type(8))) short short8;
typedef __attribute__((ext_vector_type(4))) float f32x4;

#define BB 8
#define CCH 256
#define HH 64
#define WW 64
#define HP 66
#define NPOS 4096
#define KTOT 2304

// ---- ws layout (bytes) ----
#define XT_BYTES   17842176ull                 // bf16 [8][66][66][256]
#define W2R_OFF    17842176ull                 // bf16 [256][2304]
#define WOFF2_OFF  19021824ull                 // bf16 [32][2304]
#define P_OFF      19169280ull                 // fp32 [8][9][18][4096] partials
#define OFF2_OFF   40402944ull                 // float2 [8][9][4096]
#define S_OFF      42762240ull                 // bf16 [nb][9][4096][256]
#define S_BATCH    18874368ull                 // bytes per batch

__device__ __forceinline__ float bf2f(u16 u) {
    union { u32 u; float f; } v; v.u = ((u32)u) << 16; return v.f;
}
__device__ __forceinline__ u16 f2bf(float f) {
    union { float f; u32 u; } v; v.f = f;
    u32 r = v.u + 0x7FFFu + ((v.u >> 16) & 1u);
    return (u16)(r >> 16);
}
__device__ __forceinline__ u32 pk2(float a, float b) {
    return (u32)f2bf(a) | ((u32)f2bf(b) << 16);
}
__device__ __forceinline__ void bf2x2(u32 p, float& a, float& b) {
    union { u32 u; float f; } va, vb;
    va.u = p << 16; vb.u = p & 0xffff0000u;
    a = va.f; b = vb.f;
}
// async global->LDS, 16B per lane; LDS dest = wave-uniform base + lane*16
__device__ __forceinline__ void ldg_lds16(const u16* g, u16* l) {
    __builtin_amdgcn_global_load_lds((const __attribute__((address_space(1))) u32*)g,
                                     (__attribute__((address_space(3))) u32*)l, 16, 0, 0);
}

// ---- K0: reorder weights via LDS transpose: W2r[o][k*256+c] = w[o][c][k] ----
__global__ __launch_bounds__(256) void k_prep(const float* __restrict__ w, const float* __restrict__ w_off,
                                              u16* __restrict__ W2r, u16* __restrict__ Woff2) {
    __shared__ float L[2304];
    int t = threadIdx.x;
    if (blockIdx.x < 256) {
        int o = blockIdx.x;
        const float* src = w + (size_t)o * 2304;
#pragma unroll
        for (int j = 0; j < 9; ++j) L[j * 256 + t] = src[j * 256 + t];
        __syncthreads();
        u16* dst = W2r + (size_t)o * 2304;
#pragma unroll
        for (int k = 0; k < 9; ++k) dst[k * 256 + t] = f2bf(L[t * 9 + k]);   // stride-9: conflict-free
    } else {
        for (int o2 = 0; o2 < 32; ++o2) {
            if (o2 < 18) {
                const float* src = w_off + (size_t)o2 * 2304;
#pragma unroll
                for (int j = 0; j < 9; ++j) L[j * 256 + t] = src[j * 256 + t];
                __syncthreads();
#pragma unroll
                for (int k = 0; k < 9; ++k) Woff2[(size_t)o2 * 2304 + k * 256 + t] = f2bf(L[t * 9 + k]);
                __syncthreads();
            } else {
#pragma unroll
                for (int k = 0; k < 9; ++k) Woff2[(size_t)o2 * 2304 + k * 256 + t] = 0;
            }
        }
    }
}

// ---- K0b: zero the 1-px padding border of xT (replaces full memset) ----
__global__ void k_border(u16* __restrict__ xT) {
    int b = blockIdx.x, m = blockIdx.y;
    int y, x;
    if (m < 66)       { y = 0;  x = m; }
    else if (m < 132) { y = 65; x = m - 66; }
    else if (m < 196) { y = m - 132 + 1; x = 0; }
    else              { y = m - 196 + 1; x = 65; }
    u16* p = xT + ((size_t)(b * HP + y) * HP + x) * CCH + threadIdx.x * 4;
    uint2 zz; zz.x = 0; zz.y = 0;
    *(uint2*)p = zz;
}

// ---- K1: transpose+pad fp32 NCHW -> bf16 NHWC padded; x = batch (XCD-pinned) ----
__global__ __launch_bounds__(256) void k_transpose(const float* __restrict__ x, u16* __restrict__ xT) {
    __shared__ __align__(16) float T[64][72];
    int b = blockIdx.x, y = blockIdx.y, c0 = blockIdx.z * 64;
    int t = threadIdx.x;
    {
        int i = t >> 2, seg = t & 3;   // channel i, 16-float x-segment
        const float* src = x + (((size_t)(b * CCH + c0 + i) * HH + y) * WW) + seg * 16;
        float4 v0 = *(const float4*)(src);
        float4 v1 = *(const float4*)(src + 4);
        float4 v2 = *(const float4*)(src + 8);
        float4 v3 = *(const float4*)(src + 12);
        *(float4*)&T[i][seg * 16]      = v0;
        *(float4*)&T[i][seg * 16 + 4]  = v1;
        *(float4*)&T[i][seg * 16 + 8]  = v2;
        *(float4*)&T[i][seg * 16 + 12] = v3;
    }
    __syncthreads();
    {
        int xc = t >> 2, cs = t & 3;   // x-position xc, 16-channel segment cs
        u16* dst = xT + (((size_t)(b * HP + y + 1) * HP) + (xc + 1)) * CCH + c0 + cs * 16;
        u32 p[8];
#pragma unroll
        for (int j = 0; j < 8; ++j)
            p[j] = pk2(T[cs * 16 + 2 * j][xc], T[cs * 16 + 2 * j + 1][xc]);
        uint4 d0, d1;
        d0.x = p[0]; d0.y = p[1]; d0.z = p[2]; d0.w = p[3];
        d1.x = p[4]; d1.y = p[5]; d1.z = p[6]; d1.w = p[7];
        *(uint4*)dst = d0;
        *(uint4*)(dst + 8) = d1;
    }
}

// ---- K2: offset conv GEMM, K-split by tap; R7-style coalesced swizzled staging, BK=64 ----
__global__ __launch_bounds__(256) void k_offconv(const u16* __restrict__ xT,
                                                 const u16* __restrict__ Woff2,
                                                 float* __restrict__ P) {
    __shared__ __align__(16) u16 AS[2][2048];   // [32 row][64 k] swizzled chunks, 4KB/buf
    __shared__ __align__(16) u16 BS[2][8192];   // [128 row][64 k] swizzled chunks, 16KB/buf
    int b = blockIdx.x, k9 = blockIdx.y;
    int pos0 = blockIdx.z * 128;
    int ky = k9 / 3, kx = k9 % 3;
    int t = threadIdx.x, lane = t & 63, wv = t >> 6;

    // staging geometry (R7 pattern): instr covers 8 rows x 128B; lane: srow=lane>>3, chunk=lane&7
    int srow = lane >> 3;
    int sw8 = ((lane & 7) ^ srow) << 3;          // swizzled k-chunk offset (u16 elems)
    const u16* pA = Woff2 + (size_t)k9 * 256;    // + row*KTOT + cs*64 + sw8
    const u16* pXb = xT + (size_t)b * HP * HP * CCH;

    f32x4 acc[2][2];
    f32x4 z = {0.f, 0.f, 0.f, 0.f};
    acc[0][0] = z; acc[0][1] = z; acc[1][0] = z; acc[1][1] = z;

    // stage step cs into buffer d: A = 1 instr/wave (4 total), B = 4 instrs/wave (16 total)
    auto stage = [&](int cs, int d) {
        int koff = cs * 64;
        {   // A: rows wv*8 + srow (0..31)
            int row = wv * 8 + srow;
            ldg_lds16(pA + (size_t)row * KTOT + koff + sw8, &AS[d][wv * 512]);
        }
#pragma unroll
        for (int i = 0; i < 4; ++i) {            // B: instr = wv*4+i covers pos rows inst*8+srow
            int inst = wv * 4 + i;
            int rowg = pos0 + inst * 8 + srow;
            int py_ = rowg >> 6, px_ = rowg & 63;
            const u16* g = pXb + (((size_t)(py_ + ky) * HP) + px_ + kx) * CCH + koff + sw8;
            ldg_lds16(g, &BS[d][inst * 512]);
        }
    };

    stage(0, 0);
    __syncthreads();

    int buf = 0;
    int m = lane & 15, q = lane >> 4, key = lane & 7;
    for (int cs = 0; cs < 4; ++cs) {
        if (cs < 3) stage(cs + 1, buf ^ 1);
#pragma unroll
        for (int j = 0; j < 2; ++j) {
            int slot8 = (((j * 4 + q) ^ key) << 3);
            short8 a0 = *(const short8*)&AS[buf][m * 64 + slot8];
            short8 a1 = *(const short8*)&AS[buf][(16 + m) * 64 + slot8];
            short8 b0 = *(const short8*)&BS[buf][(wv * 32 + m) * 64 + slot8];
            short8 b1 = *(const short8*)&BS[buf][(wv * 32 + 16 + m) * 64 + slot8];
            acc[0][0] = __builtin_amdgcn_mfma_f32_16x16x32_bf16(a0, b0, acc[0][0], 0, 0, 0);
            acc[0][1] = __builtin_amdgcn_mfma_f32_16x16x32_bf16(a0, b1, acc[0][1], 0, 0, 0);
            acc[1][0] = __builtin_amdgcn_mfma_f32_16x16x32_bf16(a1, b0, acc[1][0], 0, 0, 0);
            acc[1][1] = __builtin_amdgcn_mfma_f32_16x16x32_bf16(a1, b1, acc[1][1], 0, 0, 0);
        }
        __syncthreads();
        buf ^= 1;
    }
    int nn = lane & 15;
    float* Pp = P + (size_t)(b * 9 + k9) * 18 * NPOS;
#pragma unroll
    for (int ao = 0; ao < 2; ++ao)
#pragma unroll
        for (int bn = 0; bn < 2; ++bn) {
            int pos = pos0 + wv * 32 + bn * 16 + nn;
#pragma unroll
            for (int r = 0; r < 4; ++r) {
                int o = ao * 16 + q * 4 + r;
                if (o < 18) Pp[o * NPOS + pos] = acc[ao][bn][r];
            }
        }
}

// ---- K2b: reduce 9 tap-partials + bias -> off2[b][tap][pos] = (dy,dx) ----
__global__ __launch_bounds__(256) void k_reduce(const float* __restrict__ P,
                                                const float* __restrict__ b_off,
                                                float2* __restrict__ off2) {
    int b = blockIdx.x;
    int pos = blockIdx.y * 256 + threadIdx.x;
    float s[18];
#pragma unroll
    for (int o = 0; o < 18; ++o) s[o] = b_off[o];
    const float* Pp = P + (size_t)(b * 9) * 18 * NPOS + pos;
    for (int k9 = 0; k9 < 9; ++k9) {
#pragma unroll
        for (int o = 0; o < 18; ++o)
            s[o] += Pp[(k9 * 18 + o) * NPOS];
    }
#pragma unroll
    for (int op = 0; op < 9; ++op) {
        float2 v; v.x = s[2 * op]; v.y = s[2 * op + 1];
        off2[(((size_t)(b * 9 + op)) << 12) + pos] = v;
    }
}

// ---- K3: materialize S[bl][k9][pos][c] bf16 via 16-lane-group coalesced bilinear gather ----
__global__ __launch_bounds__(256) void k_sample(const u16* __restrict__ xT,
                                                const float2* __restrict__ off2,
                                                u16* __restrict__ S, int b0) {
    int bl = blockIdx.x, b = b0 + bl, k9 = blockIdx.y;
    int pos0 = blockIdx.z * 64;
    int t = threadIdx.x, g = t >> 4, ll = t & 15;
    int ky = k9 / 3, kx = k9 % 3;
    int bbase = b * HP * HP;

    for (int i = 0; i < 4; ++i) {
        int pos = pos0 + g + i * 16;
        int y = pos >> 6, x = pos & 63;
        float2 off = off2[(((size_t)(b * 9 + k9)) << 12) + pos];
        float pyf = (float)(y - 1 + ky) + off.x;
        float pxf = (float)(x - 1 + kx) + off.y;
        float y0f = floorf(pyf), x0f = floorf(pxf);
        int y0 = (int)y0f, x0 = (int)x0f;
        int y1 = y0 + 1, x1 = x0 + 1;
        float wy1 = pyf - y0f, wy0 = 1.f - wy1;
        float wx1 = pxf - x0f, wx0 = 1.f - wx1;
        bool vy0 = (y0 >= 0) & (y0 < HH), vy1 = (y1 >= 0) & (y1 < HH);
        bool vx0 = (x0 >= 0) & (x0 < WW), vx1 = (x1 >= 0) & (x1 < WW);
        int yc0 = min(max(y0, 0), HH - 1), yc1 = min(max(y1, 0), HH - 1);
        int xc0 = min(max(x0, 0), WW - 1), xc1 = min(max(x1, 0), WW - 1);
        float w0 = (vy0 & vx0) ? wy0 * wx0 : 0.f;
        float w1 = (vy0 & vx1) ? wy0 * wx1 : 0.f;
        float w2 = (vy1 & vx0) ? wy1 * wx0 : 0.f;
        float w3 = (vy1 & vx1) ? wy1 * wx1 : 0.f;
        const u16* g0 = xT + (size_t)((bbase + (yc0 + 1) * HP + xc0 + 1)) * CCH;
        const u16* g1 = xT + (size_t)((bbase + (yc0 + 1) * HP + xc1 + 1)) * CCH;
        const u16* g2 = xT + (size_t)((bbase + (yc1 + 1) * HP + xc0 + 1)) * CCH;
        const u16* g3 = xT + (size_t)((bbase + (yc1 + 1) * HP + xc1 + 1)) * CCH;
        u16* sp = S + ((((size_t)(bl * 9 + k9)) << 12) + pos) * CCH;
#pragma unroll
        for (int cp = 0; cp < 4; ++cp) {
            int c = cp * 64 + ll * 4;
            uint2 r0 = *(const uint2*)(g0 + c);
            uint2 r1 = *(const uint2*)(g1 + c);
            uint2 r2 = *(const uint2*)(g2 + c);
            uint2 r3 = *(const uint2*)(g3 + c);
            float f0a, f0b, f0c, f0d, f1a, f1b, f1c, f1d;
            float f2a, f2b, f2c, f2d, f3a, f3b, f3c, f3d;
            bf2x2(r0.x, f0a, f0b); bf2x2(r0.y, f0c, f0d);
            bf2x2(r1.x, f1a, f1b); bf2x2(r1.y, f1c, f1d);
            bf2x2(r2.x, f2a, f2b); bf2x2(r2.y, f2c, f2d);
            bf2x2(r3.x, f3a, f3b); bf2x2(r3.y, f3c, f3d);
            float v0 = w0 * f0a + w1 * f1a + w2 * f2a + w3 * f3a;
            float v1 = w0 * f0b + w1 * f1b + w2 * f2b + w3 * f3b;
            float v2 = w0 * f0c + w1 * f1c + w2 * f2c + w3 * f3c;
            float v3 = w0 * f0d + w1 * f1d + w2 * f2d + w3 * f3d;
            uint2 sv;
            sv.x = pk2(v0, v1); sv.y = pk2(v2, v3);
            *(uint2*)(sp + c) = sv;
        }
    }
}

// ---- K4: GEMM 128x128, BK=64, dbuf; row-major LDS + XOR-swizzled chunks (R7-verified) ----
__global__ __launch_bounds__(256) void k_gemm(const u16* __restrict__ S,
                                              const u16* __restrict__ W2r,
                                              const float* __restrict__ bias,
                                              float* __restrict__ out, int b0) {
    __shared__ __align__(16) u16 AS[2][8192];   // [128 row][64 k] row-major, swizzled chunks, 16KB
    __shared__ __align__(16) u16 BS[2][8192];
    int bl = blockIdx.x, b = b0 + bl;
    int o0 = blockIdx.y * 128;
    int pos0 = blockIdx.z * 128;
    int t = threadIdx.x, lane = t & 63, wv = t >> 6;
    int wr = wv >> 1, wc = wv & 1;

    // staging lane geometry: instr inst covers rows inst*8..+8; lane: row=+lane>>3, slot=lane&7
    int srow = lane >> 3;                       // 0..7 row-within-instr (also swizzle key)
    int sw8 = ((lane & 7) ^ srow) << 3;         // swizzled global chunk offset (u16 elems)
    const u16* pA = W2r + (size_t)o0 * KTOT;    // + row*KTOT + koff + sw8
    const u16* pSb = S + (((size_t)(bl * 9)) << 12) * CCH;

    f32x4 acc[4][4];
    f32x4 z = {0.f, 0.f, 0.f, 0.f};
#pragma unroll
    for (int i = 0; i < 4; ++i)
#pragma unroll
        for (int j = 0; j < 4; ++j) acc[i][j] = z;

    // ---- stage step s into buf d ----
    auto stage = [&](int s, int d) {
        int k9 = s >> 2, cs = s & 3;
        int koffA = k9 * 256 + cs * 64;
        const u16* pB = pSb + ((size_t)k9 << 12) * CCH + cs * 64;
#pragma unroll
        for (int i = 0; i < 4; ++i) {
            int inst = wv * 4 + i;
            int row = inst * 8 + srow;
            ldg_lds16(pA + (size_t)row * KTOT + koffA + sw8, &AS[d][inst * 512]);
            ldg_lds16(pB + (size_t)(pos0 + row) * CCH + sw8, &BS[d][inst * 512]);
        }
    };

    stage(0, 0);
    __syncthreads();

    int buf = 0;
    int m = lane & 15, q = lane >> 4, key = lane & 7;
    for (int step = 0; step < 36; ++step) {
        if (step < 35) stage(step + 1, buf ^ 1);
#pragma unroll
        for (int j = 0; j < 2; ++j) {
            int slot8 = (((j * 4 + q) ^ key) << 3);
            short8 af[4], bfr[4];
#pragma unroll
            for (int ao = 0; ao < 4; ++ao)
                af[ao] = *(const short8*)&AS[buf][(wr * 64 + ao * 16 + m) * 64 + slot8];
#pragma unroll
            for (int bn = 0; bn < 4; ++bn)
                bfr[bn] = *(const short8*)&BS[buf][(wc * 64 + bn * 16 + m) * 64 + slot8];
#pragma unroll
            for (int ao = 0; ao < 4; ++ao)
#pragma unroll
                for (int bn = 0; bn < 4; ++bn)
                    acc[ao][bn] = __builtin_amdgcn_mfma_f32_16x16x32_bf16(af[ao], bfr[bn], acc[ao][bn], 0, 0, 0);
        }
        __syncthreads();
        buf ^= 1;
    }

    // epilogue: bias + sigmoid -> fp32 NCHW
    int nn = lane & 15;
#pragma unroll
    for (int ao = 0; ao < 4; ++ao) {
        int ob = o0 + wr * 64 + ao * 16 + q * 4;
#pragma unroll
        for (int bn = 0; bn < 4; ++bn) {
            int pos = pos0 + wc * 64 + bn * 16 + nn;
#pragma unroll
            for (int r = 0; r < 4; ++r) {
                float v = acc[ao][bn][r] + bias[ob + r];
                float sg = 1.0f / (1.0f + __expf(-v));
                out[(size_t)((b * CCH + ob + r) * NPOS) + pos] = sg;
            }
        }
    }
}

extern "C" void kernel_launch(void* const* d_in, const int* in_sizes, int n_in,
                              void* d_out, int out_size, void* d_ws, size_t ws_size,
                              hipStream_t stream) {
    const float* x     = (const float*)d_in[0];
    const float* w_off = (const float*)d_in[1];
    const float* b_off = (const float*)d_in[2];
    const float* w     = (const float*)d_in[3];
    const float* bias  = (const float*)d_in[4];
    float* out = (float*)d_out;

    char* ws = (char*)d_ws;
    u16*    xT    = (u16*)ws;
    u16*    W2r   = (u16*)(ws + W2R_OFF);
    u16*    Woff2 = (u16*)(ws + WOFF2_OFF);
    float*  P     = (float*)(ws + P_OFF);
    float2* off2  = (float2*)(ws + OFF2_OFF);
    u16*    S     = (u16*)(ws + S_OFF);

    // batches per S-pass, adaptive to ws size
    int nb = 8;
    while (nb > 1 && ws_size < S_OFF + (size_t)nb * S_BATCH) nb >>= 1;
    if (ws_size < S_OFF + S_BATCH) return;

    k_prep<<<257, 256, 0, stream>>>(w, w_off, W2r, Woff2);
    k_border<<<dim3(8, 260), 64, 0, stream>>>(xT);
    k_transpose<<<dim3(8, 64, 4), 256, 0, stream>>>(x, xT);
    k_offconv<<<dim3(8, 9, 32), 256, 0, stream>>>(xT, Woff2, P);
    k_reduce<<<dim3(8, 16), 256, 0, stream>>>(P, b_off, off2);
    for (int p = 0; p < 8; p += nb) {
        k_sample<<<dim3(nb, 9, 64), 256, 0, stream>>>(xT, off2, S, p);
        k_gemm<<<dim3(nb, 2, 32), 256, 0, stream>>>(S, W2r, bias, out, p);
    }
}